// Round 2
// baseline (946.902 us; speedup 1.0000x reference)
//
#include <hip/hip_runtime.h>

#define NT 64      // tiles (8x8)
#define B_ 32
#define C_ 32
#define H_ 160
#define W_ 160
#define TH 20
#define TW 20
#define NPIX (TH*TW)    // 400
#define NRED (B_*NPIX)  // 12800 elements reduced per (tile, channel)
#define EPS 1e-5f

// ---------------- Kernel A: per-(tile,channel) mean / rstd ----------------
__global__ __launch_bounds__(256) void stats_kernel(const float* __restrict__ x,
                                                    float* __restrict__ mean_out,
                                                    float* __restrict__ rstd_out) {
    int blk = blockIdx.x;        // tl*32 + c
    int tl = blk >> 5;
    int c  = blk & 31;
    int ti = (tl >> 3) * TH;     // tile row origin
    int tj = (tl & 7)  * TW;     // tile col origin
    float s = 0.f, s2 = 0.f;
    for (int idx = threadIdx.x; idx < NRED; idx += 256) {
        int b = idx / NPIX;
        int r = (idx / TW) % TH;
        int j = idx % TW;
        float v = x[(((b*C_ + c)*H_) + ti + r)*W_ + tj + j];
        s += v; s2 += v*v;
    }
    __shared__ float sh[256], sh2[256];
    sh[threadIdx.x] = s; sh2[threadIdx.x] = s2;
    __syncthreads();
    for (int off = 128; off > 0; off >>= 1) {
        if (threadIdx.x < off) {
            sh[threadIdx.x]  += sh[threadIdx.x + off];
            sh2[threadIdx.x] += sh2[threadIdx.x + off];
        }
        __syncthreads();
    }
    if (threadIdx.x == 0) {
        float m   = sh[0] / (float)NRED;
        float var = sh2[0] / (float)NRED - m*m;
        mean_out[blk] = m;
        rstd_out[blk] = rsqrtf(var + EPS);
    }
}

// ---------------- Kernel B: fused norm+relu+conv+bias+residual ----------------
// one block per (tile, batch); 448 threads: all stage LDS, 400 compute pixels.
// Weights read straight from OIHW conv_w: for fixed (co,cin) the 9 taps are
// contiguous + wave-uniform -> scalar loads (SGPR broadcast), no transpose
// scratch needed.
__global__ __launch_bounds__(448) void fused_kernel(
        const float* __restrict__ x,
        const float* __restrict__ gamma,
        const float* __restrict__ beta,
        const float* __restrict__ conv_w,
        const float* __restrict__ conv_b,
        const float* __restrict__ mean,
        const float* __restrict__ rstd,
        float* __restrict__ out) {
    int blk = blockIdx.x;        // tl*32 + b
    int tl = blk >> 5;
    int b  = blk & 31;
    int ti = (tl >> 3) * TH;
    int tj = (tl & 7)  * TW;

    __shared__ float hs[C_ * 22 * 22];   // zero-padded normalized+relu tile, 61,952 B
    __shared__ float scale_sh[C_], shift_sh[C_];

    if (threadIdx.x < C_) {
        int c = threadIdx.x;
        float m  = mean[tl*C_ + c];
        float rs = rstd[tl*C_ + c];
        float g  = gamma[tl*C_ + c];
        scale_sh[c] = g * rs;
        shift_sh[c] = beta[tl*C_ + c] - m * rs * g;
    }
    __syncthreads();

    // fill padded LDS tile (border = 0)
    for (int idx = threadIdx.x; idx < C_ * 484; idx += 448) {
        int c   = idx / 484;
        int rem = idx - c * 484;
        int rr  = rem / 22;
        int cc  = rem - rr * 22;
        float v = 0.f;
        if (rr >= 1 && rr <= TH && cc >= 1 && cc <= TW) {
            float xv = x[((b*C_ + c)*H_ + ti + rr - 1)*W_ + tj + cc - 1];
            v = fmaxf(xv * scale_sh[c] + shift_sh[c], 0.f);
        }
        hs[idx] = v;
    }
    __syncthreads();

    int p = threadIdx.x;
    if (p < NPIX) {
        int y  = p / TW;
        int xx = p - y * TW;
        float acc[C_];
        const float* cb = conv_b + tl*C_;
        #pragma unroll
        for (int co = 0; co < C_; ++co) acc[co] = cb[co];

        // w[tl][co][cin][ky][kx]; base for this tile:
        const float* wbase = conv_w + (long)tl * C_ * C_ * 9;

        for (int cin = 0; cin < C_; ++cin) {
            const float* hrow = hs + cin*484 + y*22 + xx;
            float hv[9];
            #pragma unroll
            for (int ky = 0; ky < 3; ++ky)
                #pragma unroll
                for (int kx = 0; kx < 3; ++kx)
                    hv[ky*3+kx] = hrow[ky*22 + kx];

            const float* wrow = wbase + cin * 9;       // + co*C_*9 per co
            #pragma unroll
            for (int co = 0; co < C_; ++co) {
                const float* wp = wrow + co * (C_ * 9);  // wave-uniform -> s_load
                #pragma unroll
                for (int k = 0; k < 9; ++k)
                    acc[co] = fmaf(hv[k], wp[k], acc[co]);
            }
        }

        // bias already added; add residual and store
        #pragma unroll
        for (int co = 0; co < C_; ++co) {
            long o = (((long)b*C_ + co)*H_ + ti + y)*W_ + tj + xx;
            out[o] = acc[co] + x[o];
        }
    }
}

extern "C" void kernel_launch(void* const* d_in, const int* in_sizes, int n_in,
                              void* d_out, int out_size, void* d_ws, size_t ws_size,
                              hipStream_t stream) {
    const float* x      = (const float*)d_in[0];
    const float* gamma  = (const float*)d_in[1];
    const float* beta   = (const float*)d_in[2];
    const float* conv_w = (const float*)d_in[3];
    const float* conv_b = (const float*)d_in[4];
    float* out = (float*)d_out;

    float* ws   = (float*)d_ws;
    float* mean = ws;                 // 2048 floats (8 KB)
    float* rstd = ws + 2048;          // 2048 floats (8 KB)

    stats_kernel<<<NT * C_, 256, 0, stream>>>(x, mean, rstd);
    fused_kernel<<<NT * B_, 448, 0, stream>>>(x, gamma, beta, conv_w, conv_b,
                                              mean, rstd, out);
}

// Round 3
// 301.312 us; speedup vs baseline: 3.1426x; 3.1426x over previous
//
#include <hip/hip_runtime.h>

#define NT 64
#define B_ 32
#define C_ 32
#define H_ 160
#define W_ 160
#define TH 20
#define TW 20
#define NPIX (TH*TW)     // 400
#define NRED (B_*NPIX)   // 12800
#define EPS 1e-5f

typedef __bf16 bf16x8 __attribute__((ext_vector_type(8)));
typedef float  f32x4  __attribute__((ext_vector_type(4)));

// ============ Kernel A: coalesced partial sums -> atomicAdd ppS/ppS2 =======
// block = (b, c) plane; 320 threads; fully-coalesced float4 row reads.
__global__ __launch_bounds__(320) void statsA_kernel(const float* __restrict__ x,
                                                     float* __restrict__ ppS,
                                                     float* __restrict__ ppS2) {
    int blk = blockIdx.x;          // b*32 + c
    int b = blk >> 5;
    int c = blk & 31;
    const float* plane = x + ((long)(b*C_ + c)) * H_ * W_;

    int tid = threadIdx.x;
    int col4 = tid % 40;           // constant f4 column for this thread
    int tc   = col4 / 5;           // constant tile-col
    int rbase = tid / 40;          // 0..7

    __shared__ float sh[320], sh2[320], shr[64], shr2[64];

    for (int tr = 0; tr < 8; ++tr) {         // tile-row strips of 20 rows
        float s = 0.f, s2 = 0.f;
        #pragma unroll
        for (int k = 0; k < 3; ++k) {
            int i = tid + 320*k;             // f4 index within strip (800 total)
            if (i < 800) {
                int row = tr*20 + rbase + 8*k;
                const float* p = plane + row*W_ + col4*4;
                float4 v = *(const float4*)p;
                s  += v.x + v.y + v.z + v.w;
                s2 += v.x*v.x + v.y*v.y + v.z*v.z + v.w*v.w;
            }
        }
        sh[tid] = s; sh2[tid] = s2;
        __syncthreads();
        if (tid < 64) {                       // tc = tid>>3, slot = tid&7
            int tcc = tid >> 3, sl = tid & 7;
            float ps = 0.f, ps2 = 0.f;
            #pragma unroll
            for (int r = 0; r < 5; ++r) {
                int t = sl*40 + tcc*5 + r;
                ps += sh[t]; ps2 += sh2[t];
            }
            shr[tid] = ps; shr2[tid] = ps2;
        }
        __syncthreads();
        if (tid < 8) {
            float ps = 0.f, ps2 = 0.f;
            #pragma unroll
            for (int sl = 0; sl < 8; ++sl) { ps += shr[tid*8 + sl]; ps2 += shr2[tid*8 + sl]; }
            int tl = tr*8 + tid;
            atomicAdd(&ppS [tl*C_ + c], ps);
            atomicAdd(&ppS2[tl*C_ + c], ps2);
        }
        __syncthreads();
    }
}

// ============ Kernel B: fused norm+relu + 9-tap MFMA conv + bias + residual
// block = (tile, batch); 512 threads (8 waves).
__global__ __launch_bounds__(512, 4) void fused_kernel(
        const float* __restrict__ x,
        const float* __restrict__ gamma,
        const float* __restrict__ beta,
        const float* __restrict__ conv_w,
        const float* __restrict__ conv_b,
        const float* __restrict__ ppS,
        const float* __restrict__ ppS2,
        float* __restrict__ out) {
    int blk = blockIdx.x;
    int tl = blk >> 5;
    int b  = blk & 31;
    int ti = (tl >> 3) * TH;
    int tj = (tl & 7)  * TW;
    int tid = threadIdx.x;

    // LDS layout (75,776 B total -> 2 blocks/CU):
    //   hlds: [22][22][32] bf16 (30,976 B)  channel-last, zero-padded halo
    //   wlds: [9][32co][32cin] bf16 (18,432 B)
    //   obuf: [32co][408] bf16 (26,112 B)
    //   scale/shift: 32 f each (256 B)
    __shared__ __align__(16) unsigned char smem[75776];
    __bf16* hlds  = (__bf16*)smem;
    __bf16* wlds  = (__bf16*)(smem + 30976);
    __bf16* obuf  = (__bf16*)(smem + 49408);
    float*  scale = (float*)(smem + 75520);
    float*  shiftv= (float*)(smem + 75648);

    // ---- phase 0: zero h halo, finalize BN coeffs, stage weights ----
    {
        unsigned int* hz = (unsigned int*)smem;
        for (int i = tid; i < 7744; i += 512) hz[i] = 0u;
    }
    if (tid < C_) {
        int c = tid;
        float s  = ppS [tl*C_ + c];
        float s2 = ppS2[tl*C_ + c];
        float m  = s / (float)NRED;
        float var = s2 / (float)NRED - m*m;
        float rs = rsqrtf(var + EPS);
        float g  = gamma[tl*C_ + c];
        scale[c]  = g * rs;
        shiftv[c] = beta[tl*C_ + c] - m * rs * g;
    }
    {
        const float* wsrc = conv_w + (long)tl * C_ * C_ * 9;
        for (int f = tid; f < C_*C_*9; f += 512) {
            int co  = f / 288;
            int rem = f - co*288;
            int cin = rem / 9;
            int tap = rem - cin*9;
            wlds[(tap*C_ + co)*C_ + cin] = (__bf16)wsrc[f];
        }
    }
    __syncthreads();

    // ---- phase 1: stage normalized+relu tile (bf16, channel-last) ----
    for (int idx = tid; idx < C_*TH*5; idx += 512) {   // 3200 float4s
        int c   = idx / 100;
        int rem = idx - c*100;
        int y   = rem / 5;
        int x4  = rem - y*5;
        const float* p = x + ((long)(b*C_ + c)*H_ + ti + y)*W_ + tj + x4*4;
        float4 v = *(const float4*)p;
        float sc = scale[c], sf = shiftv[c];
        int base = ((y+1)*22 + (x4*4 + 1)) * C_ + c;
        hlds[base        ] = (__bf16)fmaxf(v.x*sc + sf, 0.f);
        hlds[base + C_   ] = (__bf16)fmaxf(v.y*sc + sf, 0.f);
        hlds[base + 2*C_ ] = (__bf16)fmaxf(v.z*sc + sf, 0.f);
        hlds[base + 3*C_ ] = (__bf16)fmaxf(v.w*sc + sf, 0.f);
    }
    __syncthreads();

    // ---- phase 2: 9 shifted GEMMs via mfma 16x16x32 ----
    int wv   = tid >> 6;            // wave 0..7
    int lane = tid & 63;
    int mm   = lane & 15;           // A: pixel-in-chunk, B: co-in-half, D: col
    int j0   = (lane >> 4) * 8;     // k-block

    // hoist all 18 B fragments (weights), reused across chunks
    bf16x8 bfr[9][2];
    #pragma unroll
    for (int tap = 0; tap < 9; ++tap) {
        #pragma unroll
        for (int h = 0; h < 2; ++h)
            bfr[tap][h] = *(const bf16x8*)&wlds[(tap*C_ + (h*16 + mm))*C_ + j0];
    }
    float b0 = conv_b[tl*C_ + mm];
    float b1 = conv_b[tl*C_ + 16 + mm];

    for (int chunk = wv; chunk < 25; chunk += 8) {
        int p  = chunk*16 + mm;
        int py = p / 20;
        int px = p - py*20;
        f32x4 a0, a1;
        #pragma unroll
        for (int r = 0; r < 4; ++r) { a0[r] = b0; a1[r] = b1; }
        #pragma unroll
        for (int ky = 0; ky < 3; ++ky) {
            #pragma unroll
            for (int kx = 0; kx < 3; ++kx) {
                bf16x8 af = *(const bf16x8*)&hlds[((py+ky)*22 + (px+kx))*C_ + j0];
                a0 = __builtin_amdgcn_mfma_f32_16x16x32_bf16(af, bfr[ky*3+kx][0], a0, 0, 0, 0);
                a1 = __builtin_amdgcn_mfma_f32_16x16x32_bf16(af, bfr[ky*3+kx][1], a1, 0, 0, 0);
            }
        }
        // D layout: col = lane&15 (co), row = (lane>>4)*4 + r (pixel-in-chunk)
        #pragma unroll
        for (int r = 0; r < 4; ++r) {
            int pix = chunk*16 + (lane >> 4)*4 + r;
            obuf[mm*408 + pix]        = (__bf16)a0[r];
            obuf[(16 + mm)*408 + pix] = (__bf16)a1[r];
        }
    }
    __syncthreads();

    // ---- phase 3: coalesced store with residual ----
    for (int idx = tid; idx < C_*NPIX; idx += 512) {
        int co = idx / NPIX;
        int p  = idx - co*NPIX;
        int y  = p / 20;
        int xx = p - y*20;
        long o = ((long)(b*C_ + co)*H_ + ti + y)*W_ + tj + xx;
        out[o] = (float)obuf[co*408 + p] + x[o];
    }
}

extern "C" void kernel_launch(void* const* d_in, const int* in_sizes, int n_in,
                              void* d_out, int out_size, void* d_ws, size_t ws_size,
                              hipStream_t stream) {
    const float* x      = (const float*)d_in[0];
    const float* gamma  = (const float*)d_in[1];
    const float* beta   = (const float*)d_in[2];
    const float* conv_w = (const float*)d_in[3];
    const float* conv_b = (const float*)d_in[4];
    float* out = (float*)d_out;

    float* ppS  = (float*)d_ws;          // 2048 floats
    float* ppS2 = ppS + NT*C_;           // 2048 floats

    hipMemsetAsync(d_ws, 0, 2 * NT * C_ * sizeof(float), stream);
    statsA_kernel<<<B_ * C_, 320, 0, stream>>>(x, ppS, ppS2);
    fused_kernel<<<NT * B_, 512, 0, stream>>>(x, gamma, beta, conv_w, conv_b,
                                              ppS, ppS2, out);
}

// Round 4
// 273.797 us; speedup vs baseline: 3.4584x; 1.1005x over previous
//
#include <hip/hip_runtime.h>

#define NT 64
#define B_ 32
#define C_ 32
#define H_ 160
#define W_ 160
#define TH 20
#define TW 20
#define NPIX (TH*TW)     // 400
#define NRED (B_*NPIX)   // 12800
#define EPS 1e-5f

#define HP 40            // hlds pixel stride (bf16) = 20 dwords -> bank-friendly
#define OP 404           // obuf co stride (bf16) = 202 dwords === 10 mod 32

typedef __bf16 bf16x8 __attribute__((ext_vector_type(8)));
typedef __bf16 bf16x4 __attribute__((ext_vector_type(4)));
typedef float  f32x4  __attribute__((ext_vector_type(4)));

// ============ Kernel A: per-(b,c)-plane coalesced stats, 1 barrier =========
__global__ __launch_bounds__(320) void statsA_kernel(const float* __restrict__ x,
                                                     float* __restrict__ ppS,
                                                     float* __restrict__ ppS2) {
    int blk = blockIdx.x;          // b*32 + c
    int b = blk >> 5;
    int c = blk & 31;
    const float* plane = x + ((long)(b*C_ + c)) * H_ * W_;

    int tid   = threadIdx.x;
    int col4  = tid % 40;          // f4 column (0..39), constant per thread
    int rbase = tid / 40;          // 0..7

    __shared__ float sh [8 * 321];
    __shared__ float sh2[8 * 321];

    #pragma unroll
    for (int tr = 0; tr < 8; ++tr) {
        float s = 0.f, s2 = 0.f;
        #pragma unroll
        for (int k = 0; k < 3; ++k) {
            int r20 = rbase + 8*k;
            if (r20 < 20) {
                int row = tr*20 + r20;
                float4 v = *(const float4*)(plane + row*W_ + col4*4);
                s  += v.x + v.y + v.z + v.w;
                s2 += v.x*v.x + v.y*v.y + v.z*v.z + v.w*v.w;
            }
        }
        sh [tr*321 + tid] = s;
        sh2[tr*321 + tid] = s2;
    }
    __syncthreads();

    if (tid < 64) {
        int tr = tid >> 3, tc = tid & 7;
        float ps = 0.f, ps2 = 0.f;
        #pragma unroll
        for (int rb = 0; rb < 8; ++rb)
            #pragma unroll
            for (int c5 = 0; c5 < 5; ++c5) {
                int t = tr*321 + rb*40 + tc*5 + c5;
                ps += sh[t]; ps2 += sh2[t];
            }
        int tl = tr*8 + tc;
        atomicAdd(&ppS [tl*C_ + c], ps);
        atomicAdd(&ppS2[tl*C_ + c], ps2);
    }
}

// ============ Kernel B: fused norm+relu + 9-tap MFMA conv + bias + residual
__global__ __launch_bounds__(512, 4) void fused_kernel(
        const float* __restrict__ x,
        const float* __restrict__ gamma,
        const float* __restrict__ beta,
        const float* __restrict__ conv_w,
        const float* __restrict__ conv_b,
        const float* __restrict__ ppS,
        const float* __restrict__ ppS2,
        float* __restrict__ out) {
    int blk = blockIdx.x;
    int tl = blk >> 5;
    int b  = blk & 31;
    int ti = (tl >> 3) * TH;
    int tj = (tl & 7)  * TW;
    int tid = threadIdx.x;

    // LDS layout (64,832 B -> 2 blocks/CU):
    //   hlds: [484 pix][40] bf16, zero-padded halo, pad channels 32..39 unused
    //   wlds: [9 tap][32 co][40] bf16 at +38,720
    //   obuf: [32 co][404 pix] bf16, ALIASES wlds (valid after hoist barrier)
    __shared__ __align__(16) unsigned char smem[64832];
    __bf16* hlds   = (__bf16*)smem;
    __bf16* wlds   = (__bf16*)(smem + 38720);
    __bf16* obuf   = (__bf16*)(smem + 38720);
    float*  scale  = (float*)(smem + 64576);
    float*  shiftv = (float*)(smem + 64704);

    // ---- phase 0: zero hlds, finalize BN coeffs, stage weights ----
    {
        uint4* hz = (uint4*)smem;
        for (int i = tid; i < 2420; i += 512) hz[i] = uint4{0,0,0,0};
    }
    if (tid < C_) {
        int c = tid;
        float s   = ppS [tl*C_ + c];
        float s2  = ppS2[tl*C_ + c];
        float m   = s / (float)NRED;
        float var = s2 / (float)NRED - m*m;
        float rs  = rsqrtf(var + EPS);
        float g   = gamma[tl*C_ + c];
        scale[c]  = g * rs;
        shiftv[c] = beta[tl*C_ + c] - m * rs * g;
    }
    {
        const float* wsrc = conv_w + (long)tl * C_ * C_ * 9;
        for (int f = tid; f < C_*C_*9; f += 512) {
            int co  = f / 288;
            int rem = f - co*288;
            int cin = rem / 9;
            int tap = rem - cin*9;
            wlds[(tap*C_ + co)*HP + cin] = (__bf16)wsrc[f];
        }
    }
    __syncthreads();

    // ---- phase 1: stage normalized+relu tile (bf16, channel-minor) ----
    for (int idx = tid; idx < C_*TH*5; idx += 512) {   // 3200 float4s
        int c   = idx / 100;
        int rem = idx - c*100;
        int y   = rem / 5;
        int x4  = rem - y*5;
        const float* p = x + ((long)(b*C_ + c)*H_ + ti + y)*W_ + tj + x4*4;
        float4 v = *(const float4*)p;
        float sc = scale[c], sf = shiftv[c];
        int base = ((y+1)*22 + (x4*4 + 1)) * HP + c;
        hlds[base         ] = (__bf16)fmaxf(v.x*sc + sf, 0.f);
        hlds[base +   HP  ] = (__bf16)fmaxf(v.y*sc + sf, 0.f);
        hlds[base + 2*HP  ] = (__bf16)fmaxf(v.z*sc + sf, 0.f);
        hlds[base + 3*HP  ] = (__bf16)fmaxf(v.w*sc + sf, 0.f);
    }
    __syncthreads();

    // ---- phase 2a: hoist B fragments (weights) + bias into registers ----
    int lane = tid & 63;
    int wv   = tid >> 6;            // wave 0..7
    int mm   = lane & 15;
    int jg   = lane >> 4;           // 0..3
    int j0   = jg * 8;

    bf16x8 bfr[9][2];
    #pragma unroll
    for (int tap = 0; tap < 9; ++tap) {
        #pragma unroll
        for (int h = 0; h < 2; ++h)
            bfr[tap][h] = *(const bf16x8*)&wlds[(tap*C_ + (h*16 + mm))*HP + j0];
    }
    float b0 = conv_b[tl*C_ + mm];
    float b1 = conv_b[tl*C_ + 16 + mm];
    __syncthreads();   // all waves hoisted; obuf may now overwrite wlds

    // ---- phase 2b: 9 shifted GEMMs via mfma 16x16x32, write obuf ----
    for (int chunk = wv; chunk < 25; chunk += 8) {
        int p  = chunk*16 + mm;
        int py = p / 20;
        int px = p - py*20;
        f32x4 a0, a1;
        #pragma unroll
        for (int r = 0; r < 4; ++r) { a0[r] = b0; a1[r] = b1; }
        #pragma unroll
        for (int ky = 0; ky < 3; ++ky) {
            #pragma unroll
            for (int kx = 0; kx < 3; ++kx) {
                bf16x8 af = *(const bf16x8*)&hlds[((py+ky)*22 + (px+kx))*HP + j0];
                a0 = __builtin_amdgcn_mfma_f32_16x16x32_bf16(af, bfr[ky*3+kx][0], a0, 0, 0, 0);
                a1 = __builtin_amdgcn_mfma_f32_16x16x32_bf16(af, bfr[ky*3+kx][1], a1, 0, 0, 0);
            }
        }
        // D: col = lane&15 (co), row = jg*4 + r (pixel) -> 4 consecutive pix
        bf16x4 o0, o1;
        #pragma unroll
        for (int r = 0; r < 4; ++r) { o0[r] = (__bf16)a0[r]; o1[r] = (__bf16)a1[r]; }
        int pb = chunk*16 + jg*4;
        *(bf16x4*)&obuf[mm*OP + pb]        = o0;
        *(bf16x4*)&obuf[(16 + mm)*OP + pb] = o1;
    }
    __syncthreads();

    // ---- phase 3: coalesced float4 store with residual ----
    for (int idx = tid; idx < C_*NPIX/4; idx += 512) {   // 3200
        int co = idx / 100;
        int q  = idx - co*100;
        int y  = q / 5;
        int x4 = q - y*5;
        bf16x4 v = *(const bf16x4*)&obuf[co*OP + y*20 + x4*4];
        long o = (((long)(b*C_ + co))*H_ + ti + y)*W_ + tj + x4*4;
        float4 xr = *(const float4*)&x[o];
        float4 ov;
        ov.x = (float)v[0] + xr.x;
        ov.y = (float)v[1] + xr.y;
        ov.z = (float)v[2] + xr.z;
        ov.w = (float)v[3] + xr.w;
        *(float4*)&out[o] = ov;
    }
}

extern "C" void kernel_launch(void* const* d_in, const int* in_sizes, int n_in,
                              void* d_out, int out_size, void* d_ws, size_t ws_size,
                              hipStream_t stream) {
    const float* x      = (const float*)d_in[0];
    const float* gamma  = (const float*)d_in[1];
    const float* beta   = (const float*)d_in[2];
    const float* conv_w = (const float*)d_in[3];
    const float* conv_b = (const float*)d_in[4];
    float* out = (float*)d_out;

    float* ppS  = (float*)d_ws;          // 2048 floats
    float* ppS2 = ppS + NT*C_;           // 2048 floats

    hipMemsetAsync(d_ws, 0, 2 * NT * C_ * sizeof(float), stream);
    statsA_kernel<<<B_ * C_, 320, 0, stream>>>(x, ppS, ppS2);
    fused_kernel<<<NT * B_, 512, 0, stream>>>(x, gamma, beta, conv_w, conv_b,
                                              ppS, ppS2, out);
}